// Round 3
// 713.299 us; speedup vs baseline: 1.0096x; 1.0096x over previous
//
#include <hip/hip_runtime.h>
#include <math.h>

#define BB 8
#define NN 50000
#define FF 256
#define KK 1024
#define CHUNK 400
#define NCHUNK 125   // 125 * 400 = 50000 exactly
#define NIT (CHUNK / 16)

// ---------- helpers ----------
__device__ __forceinline__ unsigned long long key64(double x) {
    unsigned long long u = (unsigned long long)__double_as_longlong(x);
    u ^= (u & 0x8000000000000000ull) ? 0xFFFFFFFFFFFFFFFFull : 0x8000000000000000ull;
    return u;
}
__device__ __forceinline__ double key_to_double(unsigned long long k) {
    unsigned long long u = (k & 0x8000000000000000ull) ? (k ^ 0x8000000000000000ull) : ~k;
    return __longlong_as_double((long long)u);
}

// ---------- zero the global histogram (ws is poisoned 0xAA) ----------
__global__ __launch_bounds__(1024) void zero_kernel(unsigned int* __restrict__ p, int n) {
    int i = blockIdx.x * 1024 + threadIdx.x;
    if (i < n) p[i] = 0u;
}

// ---------- phase 1: scores + fused 11-bit radix histogram ----------
// One block per (batch, 400-row chunk). 16-lane-group layout — lane group
// g = lane>>4 owns one row; lane s = lane&15 accumulates 16 elements in fp64;
// ONE shared 4-step fp64 butterfly reduces all 4 rows of the wave at once
// (8 ds-instrs per 4 rows vs 48 in the old wave-per-row butterfly). Scorer is
// pre-converted to f64 registers (halves cvt count); row loads 2-stage pipelined.
__global__ __launch_bounds__(256) void score_kernel(const float* __restrict__ emb,
                                                    const float* __restrict__ mask,
                                                    const float* __restrict__ scorer,
                                                    double* __restrict__ scores,
                                                    unsigned int* __restrict__ ghist) {
    const int b    = blockIdx.x / NCHUNK;
    const int c    = blockIdx.x % NCHUNK;
    const int n0   = c * CHUNK;
    const int lane = threadIdx.x & 63;
    const int wave = threadIdx.x >> 6;
    const int s    = lane & 15;          // element-chunk owner within the row
    const int g    = lane >> 4;          // row owner within the wave
    const int r0   = wave * 4 + g;       // row offset within each 16-row slab

    __shared__ unsigned int h[2048];
    __shared__ float smask[CHUNK];
    for (int i = threadIdx.x; i < 2048; i += 256) h[i] = 0u;
    for (int i = threadIdx.x; i < CHUNK; i += 256) smask[i] = mask[b * NN + n0 + i];
    __syncthreads();

    // scorer chunks for this lane: float4 indices s, s+16, s+32, s+48 (covers all 64
    // per 16-lane group), pre-converted to f64.
    double scd[16];
    {
        float4 f0 = ((const float4*)scorer)[s];
        float4 f1 = ((const float4*)scorer)[s + 16];
        float4 f2 = ((const float4*)scorer)[s + 32];
        float4 f3 = ((const float4*)scorer)[s + 48];
        scd[0]  = f0.x; scd[1]  = f0.y; scd[2]  = f0.z; scd[3]  = f0.w;
        scd[4]  = f1.x; scd[5]  = f1.y; scd[6]  = f1.z; scd[7]  = f1.w;
        scd[8]  = f2.x; scd[9]  = f2.y; scd[10] = f2.z; scd[11] = f2.w;
        scd[12] = f3.x; scd[13] = f3.y; scd[14] = f3.z; scd[15] = f3.w;
    }
    double n2 = 0.0;
    #pragma unroll
    for (int e = 0; e < 16; ++e) n2 += scd[e] * scd[e];
    #pragma unroll
    for (int off = 8; off; off >>= 1) n2 += __shfl_xor(n2, off, 64);
    const double inv_norm = 1.0 / sqrt(n2);

    const float* base  = emb + ((long)b * NN + n0) * FF;
    double*      sbase = scores + (long)b * NN + n0;

    auto step = [&](int it, const float4* vv) {
        double d = 0.0;
        #pragma unroll
        for (int i2 = 0; i2 < 4; ++i2) {
            d += (double)vv[i2].x * scd[4 * i2 + 0] + (double)vv[i2].y * scd[4 * i2 + 1] +
                 (double)vv[i2].z * scd[4 * i2 + 2] + (double)vv[i2].w * scd[4 * i2 + 3];
        }
        // one 4-step butterfly reduces all 4 rows of the wave simultaneously
        #pragma unroll
        for (int off = 8; off; off >>= 1) d += __shfl_xor(d, off, 64);
        if (s == 0) {
            const int row = it * 16 + r0;
            double sv = d * inv_norm + (double)smask[row];
            sbase[row] = sv;
            atomicAdd(&h[(unsigned)(key64(sv) >> 53)], 1u);
        }
    };

    const float* rp = base + r0 * FF;
    float4 v[4], w[4];
    #pragma unroll
    for (int i = 0; i < 4; ++i) v[i] = ((const float4*)rp)[s + 16 * i];

    for (int it = 0; it < NIT - 1; ++it) {
        rp += 16 * FF;
        #pragma unroll
        for (int i = 0; i < 4; ++i) w[i] = ((const float4*)rp)[s + 16 * i];  // prefetch next slab
        step(it, v);
        #pragma unroll
        for (int i = 0; i < 4; ++i) v[i] = w[i];
    }
    step(NIT - 1, v);

    __syncthreads();
    unsigned int* gh = ghist + b * 2048;
    for (int i = threadIdx.x; i < 2048; i += 256) {
        unsigned int vv = h[i];
        if (vv) atomicAdd(&gh[i], vv);
    }
}

// ---------- phase 2: per-batch exact top-K (desc value, ties -> asc index) ----------
// VERIFIED baseline version (56 KB LDS, 3 global passes). One 1024-thread block
// per batch. Starts from precomputed hist1; one in-LDS suffix scan picks bin1;
// one score scan builds hist2 (bits 52..42) restricted to bin1; a second suffix
// scan picks bin2; one scan collects the <=4096 candidate superset; O(M^2) rank
// (LDS broadcast, no barriers) emits order.
__global__ __launch_bounds__(1024) void select_kernel(const double* __restrict__ scores,
                                                      const unsigned int* __restrict__ ghist,
                                                      int* __restrict__ topk_idx,
                                                      float* __restrict__ gate) {
    const int b   = blockIdx.x;
    const int tid = threadIdx.x;
    const double* sc = scores + (long)b * NN;

    __shared__ unsigned int h[2048];
    __shared__ unsigned long long keyA[4096];
    __shared__ int idxA[4096];
    __shared__ int bin1_s, need2_s, bin2_s;
    __shared__ unsigned int cnt;

    const int i0 = tid, i1 = tid + 1024;

    h[i0] = ghist[b * 2048 + i0];
    h[i1] = ghist[b * 2048 + i1];
    if (tid == 0) cnt = 0u;
    __syncthreads();

    // suffix scan #1
    for (int off = 1; off < 2048; off <<= 1) {
        unsigned a0 = (i0 + off < 2048) ? h[i0 + off] : 0u;
        unsigned a1 = (i1 + off < 2048) ? h[i1 + off] : 0u;
        __syncthreads();
        h[i0] += a0; h[i1] += a1;
        __syncthreads();
    }
    if (h[i0] >= (unsigned)KK && (i0 == 2047 || h[i0 + 1] < (unsigned)KK)) {
        bin1_s = i0; need2_s = KK - (int)((i0 == 2047) ? 0u : h[i0 + 1]);
    }
    if (h[i1] >= (unsigned)KK && (i1 == 2047 || h[i1 + 1] < (unsigned)KK)) {
        bin1_s = i1; need2_s = KK - (int)((i1 == 2047) ? 0u : h[i1 + 1]);
    }
    __syncthreads();
    const unsigned long long bin1 = (unsigned long long)bin1_s;
    const unsigned need2 = (unsigned)need2_s;

    // hist2 over bits 52..42, restricted to bin1
    h[i0] = 0u; h[i1] = 0u;
    __syncthreads();
    for (int i = tid; i < NN / 2; i += 1024) {
        double2 v = ((const double2*)sc)[i];
        unsigned long long k0 = key64(v.x), k1 = key64(v.y);
        if ((k0 >> 53) == bin1) atomicAdd(&h[(unsigned)((k0 >> 42) & 2047ull)], 1u);
        if ((k1 >> 53) == bin1) atomicAdd(&h[(unsigned)((k1 >> 42) & 2047ull)], 1u);
    }
    __syncthreads();

    // suffix scan #2
    for (int off = 1; off < 2048; off <<= 1) {
        unsigned a0 = (i0 + off < 2048) ? h[i0 + off] : 0u;
        unsigned a1 = (i1 + off < 2048) ? h[i1 + off] : 0u;
        __syncthreads();
        h[i0] += a0; h[i1] += a1;
        __syncthreads();
    }
    if (h[i0] >= need2 && (i0 == 2047 || h[i0 + 1] < need2)) bin2_s = i0;
    if (h[i1] >= need2 && (i1 == 2047 || h[i1 + 1] < need2)) bin2_s = i1;
    __syncthreads();
    const unsigned long long pfx = (bin1 << 11) | (unsigned long long)bin2_s;

    // collect candidate superset (22-bit prefix >= pfx)
    for (int i = tid; i < NN / 2; i += 1024) {
        double2 v = ((const double2*)sc)[i];
        unsigned long long k0 = key64(v.x), k1 = key64(v.y);
        if ((k0 >> 42) >= pfx) {
            unsigned p = atomicAdd(&cnt, 1u);
            if (p < 4096u) { keyA[p] = k0; idxA[p] = 2 * i; }
        }
        if ((k1 >> 42) >= pfx) {
            unsigned p = atomicAdd(&cnt, 1u);
            if (p < 4096u) { keyA[p] = k1; idxA[p] = 2 * i + 1; }
        }
    }
    __syncthreads();
    const int M = (int)(cnt < 4096u ? cnt : 4096u);

    // O(M^2) rank: rank(i) = #{j: key_j > key_i or (key_j == key_i and idx_j < idx_i)}
    for (int i = tid; i < M; i += 1024) {
        const unsigned long long ki = keyA[i];
        const int ii = idxA[i];
        int rank = 0;
        for (int j = 0; j < M; ++j) {
            const unsigned long long kj = keyA[j];
            rank += (kj > ki) || (kj == ki && idxA[j] < ii);
        }
        if (rank < KK) {
            topk_idx[b * KK + rank] = ii;
            gate[b * KK + rank]     = tanhf((float)key_to_double(ki));
        }
    }
}

// ---------- phase 3: out[b,f,k] = emb[b, idx[b,k], f] * gate[b,k] ----------
__global__ __launch_bounds__(256) void gather_kernel(const float* __restrict__ emb,
                                                     const int* __restrict__ topk_idx,
                                                     const float* __restrict__ gate,
                                                     float* __restrict__ out) {
    const int b  = blockIdx.x >> 5;
    const int kt = blockIdx.x & 31;
    const int k0 = kt * 32;
    const int tid = threadIdx.x;

    __shared__ float tile[32][FF + 4];
    __shared__ int   s_idx[32];
    __shared__ float s_gate[32];

    if (tid < 32) {
        s_idx[tid]  = topk_idx[b * KK + k0 + tid];
        s_gate[tid] = gate[b * KK + k0 + tid];
    }
    __syncthreads();

    const int g = tid >> 6, lane = tid & 63;
    #pragma unroll
    for (int i = 0; i < 8; i++) {
        int kl = i * 4 + g;
        int row = s_idx[kl];
        float gt = s_gate[kl];
        float4 v = ((const float4*)(emb + ((long)b * NN + row) * FF))[lane];
        float* t = &tile[kl][lane * 4];
        t[0] = v.x * gt; t[1] = v.y * gt; t[2] = v.z * gt; t[3] = v.w * gt;
    }
    __syncthreads();

    const long outbase = ((long)b * FF) * KK + k0;
    #pragma unroll
    for (int c = 0; c < 32; c++) {
        int linear = c * 256 + tid;
        int f = linear >> 5;
        int k = linear & 31;
        out[outbase + (long)f * KK + k] = tile[k][f];
    }
}

extern "C" void kernel_launch(void* const* d_in, const int* in_sizes, int n_in,
                              void* d_out, int out_size, void* d_ws, size_t ws_size,
                              hipStream_t stream) {
    const float* emb    = (const float*)d_in[0];  // [B, N, F] fp32
    const float* mask   = (const float*)d_in[1];  // [B, N] fp32
    const float* scorer = (const float*)d_in[2];  // [F, 1] fp32
    float* out = (float*)d_out;                   // [B, F, K] fp32

    char* wsb = (char*)d_ws;
    double*       scores  = (double*)wsb;                               // B*N doubles = 3.2 MB
    unsigned int* ghist   = (unsigned int*)(wsb + sizeof(double) * BB * NN);
    int*          topkidx = (int*)((char*)ghist + sizeof(unsigned int) * BB * 2048);
    float*        gatep   = (float*)((char*)topkidx + sizeof(int) * BB * KK);

    zero_kernel<<<16, 1024, 0, stream>>>(ghist, BB * 2048);
    score_kernel<<<BB * NCHUNK, 256, 0, stream>>>(emb, mask, scorer, scores, ghist);
    select_kernel<<<BB, 1024, 0, stream>>>(scores, ghist, topkidx, gatep);
    gather_kernel<<<BB * 32, 256, 0, stream>>>(emb, topkidx, gatep, out);
}

// Round 4
// 650.387 us; speedup vs baseline: 1.1073x; 1.0967x over previous
//
#include <hip/hip_runtime.h>
#include <math.h>

#define BB 8
#define NN 50000
#define FF 256
#define KK 1024
#define CHUNK 400
#define NCHUNK 125   // 125 * 400 = 50000 exactly
#define NIT (CHUNK / 16)
#define CAPA 4096
#define RBLK 16      // rank blocks per batch (16 * 256 threads covers CAPA)

// ---------- helpers ----------
__device__ __forceinline__ unsigned long long key64(double x) {
    unsigned long long u = (unsigned long long)__double_as_longlong(x);
    u ^= (u & 0x8000000000000000ull) ? 0xFFFFFFFFFFFFFFFFull : 0x8000000000000000ull;
    return u;
}
__device__ __forceinline__ double key_to_double(unsigned long long k) {
    unsigned long long u = (k & 0x8000000000000000ull) ? (k ^ 0x8000000000000000ull) : ~k;
    return __longlong_as_double((long long)u);
}

// ---------- zero the global histogram (ws is poisoned 0xAA) ----------
__global__ __launch_bounds__(1024) void zero_kernel(unsigned int* __restrict__ p, int n) {
    int i = blockIdx.x * 1024 + threadIdx.x;
    if (i < n) p[i] = 0u;
}

// ---------- phase 1: scores + fused 11-bit radix histogram ----------
// (HW-verified this round at dur ~= BW floor.) 16-lane-group layout; one shared
// 4-step fp64 butterfly per 4 rows; pipelined slab loads.
__global__ __launch_bounds__(256) void score_kernel(const float* __restrict__ emb,
                                                    const float* __restrict__ mask,
                                                    const float* __restrict__ scorer,
                                                    double* __restrict__ scores,
                                                    unsigned int* __restrict__ ghist) {
    const int b    = blockIdx.x / NCHUNK;
    const int c    = blockIdx.x % NCHUNK;
    const int n0   = c * CHUNK;
    const int lane = threadIdx.x & 63;
    const int wave = threadIdx.x >> 6;
    const int s    = lane & 15;          // element-chunk owner within the row
    const int g    = lane >> 4;          // row owner within the wave
    const int r0   = wave * 4 + g;       // row offset within each 16-row slab

    __shared__ unsigned int h[2048];
    __shared__ float smask[CHUNK];
    for (int i = threadIdx.x; i < 2048; i += 256) h[i] = 0u;
    for (int i = threadIdx.x; i < CHUNK; i += 256) smask[i] = mask[b * NN + n0 + i];
    __syncthreads();

    double scd[16];
    {
        float4 f0 = ((const float4*)scorer)[s];
        float4 f1 = ((const float4*)scorer)[s + 16];
        float4 f2 = ((const float4*)scorer)[s + 32];
        float4 f3 = ((const float4*)scorer)[s + 48];
        scd[0]  = f0.x; scd[1]  = f0.y; scd[2]  = f0.z; scd[3]  = f0.w;
        scd[4]  = f1.x; scd[5]  = f1.y; scd[6]  = f1.z; scd[7]  = f1.w;
        scd[8]  = f2.x; scd[9]  = f2.y; scd[10] = f2.z; scd[11] = f2.w;
        scd[12] = f3.x; scd[13] = f3.y; scd[14] = f3.z; scd[15] = f3.w;
    }
    double n2 = 0.0;
    #pragma unroll
    for (int e = 0; e < 16; ++e) n2 += scd[e] * scd[e];
    #pragma unroll
    for (int off = 8; off; off >>= 1) n2 += __shfl_xor(n2, off, 64);
    const double inv_norm = 1.0 / sqrt(n2);

    const float* base  = emb + ((long)b * NN + n0) * FF;
    double*      sbase = scores + (long)b * NN + n0;

    auto step = [&](int it, const float4* vv) {
        double d = 0.0;
        #pragma unroll
        for (int i2 = 0; i2 < 4; ++i2) {
            d += (double)vv[i2].x * scd[4 * i2 + 0] + (double)vv[i2].y * scd[4 * i2 + 1] +
                 (double)vv[i2].z * scd[4 * i2 + 2] + (double)vv[i2].w * scd[4 * i2 + 3];
        }
        #pragma unroll
        for (int off = 8; off; off >>= 1) d += __shfl_xor(d, off, 64);
        if (s == 0) {
            const int row = it * 16 + r0;
            double sv = d * inv_norm + (double)smask[row];
            sbase[row] = sv;
            atomicAdd(&h[(unsigned)(key64(sv) >> 53)], 1u);
        }
    };

    const float* rp = base + r0 * FF;
    float4 v[4], w[4];
    #pragma unroll
    for (int i = 0; i < 4; ++i) v[i] = ((const float4*)rp)[s + 16 * i];

    for (int it = 0; it < NIT - 1; ++it) {
        rp += 16 * FF;
        #pragma unroll
        for (int i = 0; i < 4; ++i) w[i] = ((const float4*)rp)[s + 16 * i];
        step(it, v);
        #pragma unroll
        for (int i = 0; i < 4; ++i) v[i] = w[i];
    }
    step(NIT - 1, v);

    __syncthreads();
    unsigned int* gh = ghist + b * 2048;
    for (int i = threadIdx.x; i < 2048; i += 256) {
        unsigned int vv = h[i];
        if (vv) atomicAdd(&gh[i], vv);
    }
}

// ---------- phase 2a: per-batch candidate collection (verified 3-pass structure) ----------
// Identical to the verified select_kernel up through candidate collection, then
// writes the candidate set (key, idx, count) to global ws instead of ranking.
__global__ __launch_bounds__(1024) void candidates_kernel(const double* __restrict__ scores,
                                                          const unsigned int* __restrict__ ghist,
                                                          unsigned long long* __restrict__ ckey,
                                                          int* __restrict__ cidx,
                                                          unsigned int* __restrict__ ccnt) {
    const int b   = blockIdx.x;
    const int tid = threadIdx.x;
    const double* sc = scores + (long)b * NN;

    __shared__ unsigned int h[2048];
    __shared__ unsigned long long keyA[CAPA];
    __shared__ int idxA[CAPA];
    __shared__ int bin1_s, need2_s, bin2_s;
    __shared__ unsigned int cnt;

    const int i0 = tid, i1 = tid + 1024;

    h[i0] = ghist[b * 2048 + i0];
    h[i1] = ghist[b * 2048 + i1];
    if (tid == 0) cnt = 0u;
    __syncthreads();

    // suffix scan #1
    for (int off = 1; off < 2048; off <<= 1) {
        unsigned a0 = (i0 + off < 2048) ? h[i0 + off] : 0u;
        unsigned a1 = (i1 + off < 2048) ? h[i1 + off] : 0u;
        __syncthreads();
        h[i0] += a0; h[i1] += a1;
        __syncthreads();
    }
    if (h[i0] >= (unsigned)KK && (i0 == 2047 || h[i0 + 1] < (unsigned)KK)) {
        bin1_s = i0; need2_s = KK - (int)((i0 == 2047) ? 0u : h[i0 + 1]);
    }
    if (h[i1] >= (unsigned)KK && (i1 == 2047 || h[i1 + 1] < (unsigned)KK)) {
        bin1_s = i1; need2_s = KK - (int)((i1 == 2047) ? 0u : h[i1 + 1]);
    }
    __syncthreads();
    const unsigned long long bin1 = (unsigned long long)bin1_s;
    const unsigned need2 = (unsigned)need2_s;

    // hist2 over bits 52..42, restricted to bin1
    h[i0] = 0u; h[i1] = 0u;
    __syncthreads();
    for (int i = tid; i < NN / 2; i += 1024) {
        double2 v = ((const double2*)sc)[i];
        unsigned long long k0 = key64(v.x), k1 = key64(v.y);
        if ((k0 >> 53) == bin1) atomicAdd(&h[(unsigned)((k0 >> 42) & 2047ull)], 1u);
        if ((k1 >> 53) == bin1) atomicAdd(&h[(unsigned)((k1 >> 42) & 2047ull)], 1u);
    }
    __syncthreads();

    // suffix scan #2
    for (int off = 1; off < 2048; off <<= 1) {
        unsigned a0 = (i0 + off < 2048) ? h[i0 + off] : 0u;
        unsigned a1 = (i1 + off < 2048) ? h[i1 + off] : 0u;
        __syncthreads();
        h[i0] += a0; h[i1] += a1;
        __syncthreads();
    }
    if (h[i0] >= need2 && (i0 == 2047 || h[i0 + 1] < need2)) bin2_s = i0;
    if (h[i1] >= need2 && (i1 == 2047 || h[i1 + 1] < need2)) bin2_s = i1;
    __syncthreads();
    const unsigned long long pfx = (bin1 << 11) | (unsigned long long)bin2_s;

    // collect candidate superset (22-bit prefix >= pfx)
    for (int i = tid; i < NN / 2; i += 1024) {
        double2 v = ((const double2*)sc)[i];
        unsigned long long k0 = key64(v.x), k1 = key64(v.y);
        if ((k0 >> 42) >= pfx) {
            unsigned p = atomicAdd(&cnt, 1u);
            if (p < (unsigned)CAPA) { keyA[p] = k0; idxA[p] = 2 * i; }
        }
        if ((k1 >> 42) >= pfx) {
            unsigned p = atomicAdd(&cnt, 1u);
            if (p < (unsigned)CAPA) { keyA[p] = k1; idxA[p] = 2 * i + 1; }
        }
    }
    __syncthreads();
    const int M = (int)(cnt < (unsigned)CAPA ? cnt : (unsigned)CAPA);

    // write candidate set to global for the parallel rank kernel
    if (tid == 0) ccnt[b] = (unsigned)M;
    for (int i = tid; i < M; i += 1024) {
        ckey[b * CAPA + i] = keyA[i];
        cidx[b * CAPA + i] = idxA[i];
    }
}

// ---------- phase 2b: parallel O(M^2) rank ----------
// 16 blocks per batch x 256 threads. Each block stages the full candidate set
// into LDS (<=48 KB) and ranks a 256-row slice with the EXACT comparator of the
// verified baseline (key desc, idx asc) -> bit-identical output, but the DS-pipe
// work is spread over 128 CUs instead of 8.
__global__ __launch_bounds__(256) void rank_kernel(const unsigned long long* __restrict__ ckey,
                                                   const int* __restrict__ cidx,
                                                   const unsigned int* __restrict__ ccnt,
                                                   int* __restrict__ topk_idx,
                                                   float* __restrict__ gate) {
    const int b  = blockIdx.x >> 4;       // RBLK=16 blocks per batch
    const int sl = blockIdx.x & (RBLK - 1);
    const int M  = (int)ccnt[b];
    const int r0 = sl * 256;
    if (r0 >= M) return;

    __shared__ unsigned long long k_s[CAPA];
    __shared__ int i_s[CAPA];

    const unsigned long long* kb = ckey + b * CAPA;
    const int* ib = cidx + b * CAPA;
    for (int i = threadIdx.x; i < M; i += 256) { k_s[i] = kb[i]; i_s[i] = ib[i]; }
    __syncthreads();

    const int r = r0 + threadIdx.x;
    if (r < M) {
        const unsigned long long kr = k_s[r];
        const int ir = i_s[r];
        int rank = 0;
        for (int j = 0; j < M; ++j) {
            const unsigned long long kj = k_s[j];
            rank += (kj > kr) || (kj == kr && i_s[j] < ir);
        }
        if (rank < KK) {
            topk_idx[b * KK + rank] = ir;
            gate[b * KK + rank]     = tanhf((float)key_to_double(kr));
        }
    }
}

// ---------- phase 3: out[b,f,k] = emb[b, idx[b,k], f] * gate[b,k] ----------
__global__ __launch_bounds__(256) void gather_kernel(const float* __restrict__ emb,
                                                     const int* __restrict__ topk_idx,
                                                     const float* __restrict__ gate,
                                                     float* __restrict__ out) {
    const int b  = blockIdx.x >> 5;
    const int kt = blockIdx.x & 31;
    const int k0 = kt * 32;
    const int tid = threadIdx.x;

    __shared__ float tile[32][FF + 4];
    __shared__ int   s_idx[32];
    __shared__ float s_gate[32];

    if (tid < 32) {
        s_idx[tid]  = topk_idx[b * KK + k0 + tid];
        s_gate[tid] = gate[b * KK + k0 + tid];
    }
    __syncthreads();

    const int g = tid >> 6, lane = tid & 63;
    #pragma unroll
    for (int i = 0; i < 8; i++) {
        int kl = i * 4 + g;
        int row = s_idx[kl];
        float gt = s_gate[kl];
        float4 v = ((const float4*)(emb + ((long)b * NN + row) * FF))[lane];
        float* t = &tile[kl][lane * 4];
        t[0] = v.x * gt; t[1] = v.y * gt; t[2] = v.z * gt; t[3] = v.w * gt;
    }
    __syncthreads();

    const long outbase = ((long)b * FF) * KK + k0;
    #pragma unroll
    for (int c = 0; c < 32; c++) {
        int linear = c * 256 + tid;
        int f = linear >> 5;
        int k = linear & 31;
        out[outbase + (long)f * KK + k] = tile[k][f];
    }
}

extern "C" void kernel_launch(void* const* d_in, const int* in_sizes, int n_in,
                              void* d_out, int out_size, void* d_ws, size_t ws_size,
                              hipStream_t stream) {
    const float* emb    = (const float*)d_in[0];  // [B, N, F] fp32
    const float* mask   = (const float*)d_in[1];  // [B, N] fp32
    const float* scorer = (const float*)d_in[2];  // [F, 1] fp32
    float* out = (float*)d_out;                   // [B, F, K] fp32

    char* wsb = (char*)d_ws;
    double*             scores  = (double*)wsb;                                   // 3.2 MB
    unsigned int*       ghist   = (unsigned int*)(wsb + sizeof(double) * BB * NN);
    int*                topkidx = (int*)((char*)ghist + sizeof(unsigned int) * BB * 2048);
    float*              gatep   = (float*)((char*)topkidx + sizeof(int) * BB * KK);
    unsigned long long* ckey    = (unsigned long long*)((char*)gatep + sizeof(float) * BB * KK);
    int*                cidx    = (int*)((char*)ckey + sizeof(unsigned long long) * BB * CAPA);
    unsigned int*       ccnt    = (unsigned int*)((char*)cidx + sizeof(int) * BB * CAPA);

    zero_kernel<<<16, 1024, 0, stream>>>(ghist, BB * 2048);
    score_kernel<<<BB * NCHUNK, 256, 0, stream>>>(emb, mask, scorer, scores, ghist);
    candidates_kernel<<<BB, 1024, 0, stream>>>(scores, ghist, ckey, cidx, ccnt);
    rank_kernel<<<BB * RBLK, 256, 0, stream>>>(ckey, cidx, ccnt, topkidx, gatep);
    gather_kernel<<<BB * 32, 256, 0, stream>>>(emb, topkidx, gatep, out);
}